// Round 6
// baseline (105.521 us; speedup 1.0000x reference)
//
#include <hip/hip_runtime.h>
#include <math.h>

// Problem constants (setup_inputs: B=16, C=4, H=256, W=256, S=24)
constexpr int Hc = 256;
constexpr int Wc = 256;
constexpr float EPSf = 1e-6f;

__device__ __forceinline__ float comp(const float4& v, int p) {
    return p == 0 ? v.x : p == 1 ? v.y : p == 2 ? v.z : v.w;
}

// Branch-free acos for x in [0,1): Abramowitz-Stegun 4.4.45, |err|<=6.7e-5
// (tolerance 1.8e-2). Raw v_sqrt_f32.
__device__ __forceinline__ float fast_acos01(float x) {
    float t = __builtin_amdgcn_sqrtf(1.0f - x);
    float p = fmaf(fmaf(fmaf(-0.0187293f, x, 0.0742610f), x, -0.2121144f),
                   x, 1.5707288f);
    return t * p;
}

__device__ __forceinline__ float fast_sqrt(float x) {
    return __builtin_amdgcn_sqrtf(x);   // single v_sqrt_f32 (~2 ulp)
}

// One thread = 4 consecutive pixels along w (one float4 quad).
// One wave = one image row. Direct global loads, all issued first (R3
// structure — measured best). Sym loop in float2 pairs -> v_pk_fma_f32.
// Epilogue: per-block float2 partial + last-block-done final reduction
// (removes the reduce-kernel dispatch; R4 showed 1024 same-address float
// atomics serialize, so partials stay).
template<int S>
__global__ __launch_bounds__(256, 4) void sym_loss_main(
    const float* __restrict__ qp,
    const float* __restrict__ qt,
    const float* __restrict__ syms,
    float2* __restrict__ partial,
    unsigned int* __restrict__ cnt,
    float* __restrict__ out,
    double cRot, double cGrad)
{
    // XCD-grouping swizzle: consecutive logical row-groups share an XCD
    // (assumes HW round-robins blockIdx%8 across 8 XCDs; perf-only).
    int nb  = gridDim.x;                  // 1024
    int lid = (blockIdx.x & 7) * (nb >> 3) + (blockIdx.x >> 3);

    int t    = lid * 256 + threadIdx.x;
    int lane = t & 63;           // quad index within the row
    int row  = t >> 6;           // 0 .. B*H-1
    int b    = row >> 8;         // H = 256 rows per image
    int h    = row & (Hc - 1);
    int w0   = lane << 2;

    int idx0 = (b << 18) + (h << 8) + w0;   // channel-0 flat index
    // edge pad: squared differences make the direction sign irrelevant
    int dy = (h == Hc - 1) ? -Wc : Wc;      // wave-uniform
    // x-neighbor of element 3: w0+4; lane 63 (w=255 edge) -> w=254 = idx+2
    int xo = (lane == 63) ? 2 : 4;

    // ---- phase 1: issue every global load ----
    float4 Cp[4], Yp[4], Ct[4], Yt[4];
    float  xp[4], xt[4];
    #pragma unroll
    for (int c = 0; c < 4; ++c) {
        int idx = idx0 + (c << 16);
        Cp[c] = *(const float4*)(qp + idx);
        Yp[c] = *(const float4*)(qp + idx + dy);
        xp[c] = qp[idx + xo];
        Ct[c] = *(const float4*)(qt + idx);
        Yt[c] = *(const float4*)(qt + idx + dy);
        xt[c] = qt[idx + xo];
    }

    // ---- phase 2: gradient-magnitude term ----
    float gsum = 0.0f;
    #pragma unroll
    for (int c = 0; c < 4; ++c) {
        float4 C = Cp[c], Y = Yp[c], D = Ct[c], Z = Yt[c];
        float gx, gy, a, e;
        gx = C.y - C.x; gy = Y.x - C.x;
        a = fast_sqrt(fmaf(gx, gx, fmaf(gy, gy, EPSf)));
        gx = D.y - D.x; gy = Z.x - D.x;
        e = fast_sqrt(fmaf(gx, gx, fmaf(gy, gy, EPSf)));
        gsum += fabsf(a - e);

        gx = C.z - C.y; gy = Y.y - C.y;
        a = fast_sqrt(fmaf(gx, gx, fmaf(gy, gy, EPSf)));
        gx = D.z - D.y; gy = Z.y - D.y;
        e = fast_sqrt(fmaf(gx, gx, fmaf(gy, gy, EPSf)));
        gsum += fabsf(a - e);

        gx = C.w - C.z; gy = Y.z - C.z;
        a = fast_sqrt(fmaf(gx, gx, fmaf(gy, gy, EPSf)));
        gx = D.w - D.z; gy = Z.z - D.z;
        e = fast_sqrt(fmaf(gx, gx, fmaf(gy, gy, EPSf)));
        gsum += fabsf(a - e);

        gx = xp[c] - C.w; gy = Y.w - C.w;
        a = fast_sqrt(fmaf(gx, gx, fmaf(gy, gy, EPSf)));
        gx = xt[c] - D.w; gy = Z.w - D.w;
        e = fast_sqrt(fmaf(gx, gx, fmaf(gy, gy, EPSf)));
        gsum += fabsf(a - e);
    }

    // ---- phase 3: per-pixel relative quaternion (vector part negated) ----
    float rw[4], nx[4], ny[4], nz[4];
    #pragma unroll
    for (int p = 0; p < 4; ++p) {
        float a0 = comp(Cp[0], p), a1 = comp(Cp[1], p),
              a2 = comp(Cp[2], p), a3 = comp(Cp[3], p);
        float b0 = comp(Ct[0], p), b1 = comp(Ct[1], p),
              b2 = comp(Ct[2], p), b3 = comp(Ct[3], p);

        float ss1 = fmaf(a0, a0, fmaf(a1, a1, fmaf(a2, a2, a3 * a3)));
        float ss2 = fmaf(b0, b0, fmaf(b1, b1, fmaf(b2, b2, b3 * b3)));
        float i1 = __builtin_amdgcn_rsqf(ss1);   // ss >> eps^2 here
        float i2 = __builtin_amdgcn_rsqf(ss2);
        float w1 = a0 * i1, x1 = a1 * i1, y1 = a2 * i1, z1 = a3 * i1;
        float w2 = b0 * i2, x2 = b1 * i2, y2 = b2 * i2, z2 = b3 * i2;

        rw[p] =  w2 * w1 + x2 * x1 + y2 * y1 + z2 * z1;
        float rx = -w2 * x1 + x2 * w1 - y2 * z1 + z2 * y1;
        float ry = -w2 * y1 + x2 * z1 + y2 * w1 - z2 * x1;
        float rz = -w2 * z1 - x2 * y1 + y2 * x1 + z2 * w1;
        nx[p] = -rx; ny[p] = -ry; nz[p] = -rz;   // signs [1,-1,-1,-1]
    }

    // ---- phase 4: sym search in float2 pairs (v_pk_fma_f32) ----
    const float4* __restrict__ sv4 = (const float4*)syms;
    float2 rwA = {rw[0], rw[1]}, rwB = {rw[2], rw[3]};
    float2 nxA = {nx[0], nx[1]}, nxB = {nx[2], nx[3]};
    float2 nyA = {ny[0], ny[1]}, nyB = {ny[2], ny[3]};
    float2 nzA = {nz[0], nz[1]}, nzB = {nz[2], nz[3]};
    float2 mA = {0.f, 0.f}, mB = {0.f, 0.f};
    #pragma unroll
    for (int s = 0; s < S; ++s) {
        float4 sv = sv4[s];
        float2 dA, dB;
        dA.x = fmaf(nzA.x, sv.w, fmaf(nyA.x, sv.z, fmaf(nxA.x, sv.y, rwA.x * sv.x)));
        dA.y = fmaf(nzA.y, sv.w, fmaf(nyA.y, sv.z, fmaf(nxA.y, sv.y, rwA.y * sv.x)));
        dB.x = fmaf(nzB.x, sv.w, fmaf(nyB.x, sv.z, fmaf(nxB.x, sv.y, rwB.x * sv.x)));
        dB.y = fmaf(nzB.y, sv.w, fmaf(nyB.y, sv.z, fmaf(nxB.y, sv.y, rwB.y * sv.x)));
        mA.x = fmaxf(mA.x, fabsf(dA.x));
        mA.y = fmaxf(mA.y, fabsf(dA.y));
        mB.x = fmaxf(mB.x, fabsf(dB.x));
        mB.y = fmaxf(mB.y, fabsf(dB.y));
    }
    float rot = fast_acos01(fminf(mA.x, 1.0f - EPSf))
              + fast_acos01(fminf(mA.y, 1.0f - EPSf))
              + fast_acos01(fminf(mB.x, 1.0f - EPSf))
              + fast_acos01(fminf(mB.y, 1.0f - EPSf));
    // (x2 of 2*acos folded into cRot)

    // ---- phase 5: block reduce -> partial; last block finishes ----
    #pragma unroll
    for (int off = 32; off > 0; off >>= 1) {
        rot  += __shfl_down(rot,  off, 64);
        gsum += __shfl_down(gsum, off, 64);
    }
    __shared__ float s_r[4], s_g[4];
    __shared__ bool amLast;
    int wid = threadIdx.x >> 6;
    if ((threadIdx.x & 63) == 0) { s_r[wid] = rot; s_g[wid] = gsum; }
    __syncthreads();
    if (threadIdx.x == 0) {
        float2 o;
        o.x = s_r[0] + s_r[1] + s_r[2] + s_r[3];
        o.y = s_g[0] + s_g[1] + s_g[2] + s_g[3];
        partial[lid] = o;
        __threadfence();                       // release partial
        unsigned int old = atomicAdd(cnt, 1u); // device-scope
        amLast = (old == (unsigned int)(nb - 1));
    }
    __syncthreads();
    if (amLast) {
        __threadfence();                       // acquire all partials
        double r = 0.0, g = 0.0;
        for (int i = threadIdx.x; i < nb; i += 256) {
            float2 p = partial[i];
            r += (double)p.x;
            g += (double)p.y;
        }
        #pragma unroll
        for (int off = 32; off > 0; off >>= 1) {
            r += __shfl_down(r, off, 64);
            g += __shfl_down(g, off, 64);
        }
        __shared__ double d_r[4], d_g[4];
        if ((threadIdx.x & 63) == 0) { d_r[wid] = r; d_g[wid] = g; }
        __syncthreads();
        if (threadIdx.x == 0) {
            double rr = d_r[0] + d_r[1] + d_r[2] + d_r[3];
            double gg = d_g[0] + d_g[1] + d_g[2] + d_g[3];
            out[0] = (float)(rr * cRot + gg * cGrad);
        }
    }
}

// Generic-S fallback (runtime sym loop), partials + reduce kernel
__global__ __launch_bounds__(256) void sym_loss_generic(
    const float* __restrict__ qp,
    const float* __restrict__ qt,
    const float* __restrict__ syms,
    int S,
    float2* __restrict__ partial)
{
    int t    = blockIdx.x * 256 + threadIdx.x;
    int lane = t & 63;
    int row  = t >> 6;
    int b    = row >> 8;
    int h    = row & (Hc - 1);
    int w0   = lane << 2;
    int idx0 = (b << 18) + (h << 8) + w0;
    int dy = (h == Hc - 1) ? -Wc : Wc;
    int xo = (lane == 63) ? 2 : 4;

    float4 Cp[4], Yp[4], Ct[4], Yt[4];
    float  xp[4], xt[4];
    #pragma unroll
    for (int c = 0; c < 4; ++c) {
        int idx = idx0 + (c << 16);
        Cp[c] = *(const float4*)(qp + idx);
        Yp[c] = *(const float4*)(qp + idx + dy);
        xp[c] = qp[idx + xo];
        Ct[c] = *(const float4*)(qt + idx);
        Yt[c] = *(const float4*)(qt + idx + dy);
        xt[c] = qt[idx + xo];
    }
    float gsum = 0.0f;
    #pragma unroll
    for (int c = 0; c < 4; ++c) {
        float4 C = Cp[c], Y = Yp[c], D = Ct[c], Z = Yt[c];
        float gx, gy, a, e;
        gx = C.y - C.x; gy = Y.x - C.x;
        a = fast_sqrt(fmaf(gx, gx, fmaf(gy, gy, EPSf)));
        gx = D.y - D.x; gy = Z.x - D.x;
        e = fast_sqrt(fmaf(gx, gx, fmaf(gy, gy, EPSf)));
        gsum += fabsf(a - e);
        gx = C.z - C.y; gy = Y.y - C.y;
        a = fast_sqrt(fmaf(gx, gx, fmaf(gy, gy, EPSf)));
        gx = D.z - D.y; gy = Z.y - D.y;
        e = fast_sqrt(fmaf(gx, gx, fmaf(gy, gy, EPSf)));
        gsum += fabsf(a - e);
        gx = C.w - C.z; gy = Y.z - C.z;
        a = fast_sqrt(fmaf(gx, gx, fmaf(gy, gy, EPSf)));
        gx = D.w - D.z; gy = Z.z - D.z;
        e = fast_sqrt(fmaf(gx, gx, fmaf(gy, gy, EPSf)));
        gsum += fabsf(a - e);
        gx = xp[c] - C.w; gy = Y.w - C.w;
        a = fast_sqrt(fmaf(gx, gx, fmaf(gy, gy, EPSf)));
        gx = xt[c] - D.w; gy = Z.w - D.w;
        e = fast_sqrt(fmaf(gx, gx, fmaf(gy, gy, EPSf)));
        gsum += fabsf(a - e);
    }
    float rw[4], nx[4], ny[4], nz[4];
    #pragma unroll
    for (int p = 0; p < 4; ++p) {
        float a0 = comp(Cp[0], p), a1 = comp(Cp[1], p),
              a2 = comp(Cp[2], p), a3 = comp(Cp[3], p);
        float b0 = comp(Ct[0], p), b1 = comp(Ct[1], p),
              b2 = comp(Ct[2], p), b3 = comp(Ct[3], p);
        float ss1 = fmaf(a0, a0, fmaf(a1, a1, fmaf(a2, a2, a3 * a3)));
        float ss2 = fmaf(b0, b0, fmaf(b1, b1, fmaf(b2, b2, b3 * b3)));
        float i1 = __builtin_amdgcn_rsqf(ss1);
        float i2 = __builtin_amdgcn_rsqf(ss2);
        float w1 = a0 * i1, x1 = a1 * i1, y1 = a2 * i1, z1 = a3 * i1;
        float w2 = b0 * i2, x2 = b1 * i2, y2 = b2 * i2, z2 = b3 * i2;
        rw[p] =  w2 * w1 + x2 * x1 + y2 * y1 + z2 * z1;
        float rx = -w2 * x1 + x2 * w1 - y2 * z1 + z2 * y1;
        float ry = -w2 * y1 + x2 * z1 + y2 * w1 - z2 * x1;
        float rz = -w2 * z1 - x2 * y1 + y2 * x1 + z2 * w1;
        nx[p] = -rx; ny[p] = -ry; nz[p] = -rz;
    }
    const float4* __restrict__ sv4 = (const float4*)syms;
    float maxw[4] = {0.f, 0.f, 0.f, 0.f};
    for (int s = 0; s < S; ++s) {
        float4 sv = sv4[s];
        #pragma unroll
        for (int p = 0; p < 4; ++p) {
            float d = fmaf(nz[p], sv.w,
                      fmaf(ny[p], sv.z,
                      fmaf(nx[p], sv.y, rw[p] * sv.x)));
            maxw[p] = fmaxf(maxw[p], fabsf(d));
        }
    }
    float rot = 0.0f;
    #pragma unroll
    for (int p = 0; p < 4; ++p)
        rot += fast_acos01(fminf(maxw[p], 1.0f - EPSf));
    #pragma unroll
    for (int off = 32; off > 0; off >>= 1) {
        rot  += __shfl_down(rot,  off, 64);
        gsum += __shfl_down(gsum, off, 64);
    }
    __shared__ float s_r[4], s_g[4];
    int wid = threadIdx.x >> 6;
    if ((threadIdx.x & 63) == 0) { s_r[wid] = rot; s_g[wid] = gsum; }
    __syncthreads();
    if (threadIdx.x == 0) {
        float2 o;
        o.x = s_r[0] + s_r[1] + s_r[2] + s_r[3];
        o.y = s_g[0] + s_g[1] + s_g[2] + s_g[3];
        partial[blockIdx.x] = o;
    }
}

__global__ __launch_bounds__(256) void sym_loss_reduce(
    const float2* __restrict__ partial, int nblocks,
    float* __restrict__ out, double cRot, double cGrad)
{
    double r = 0.0, g = 0.0;
    for (int i = threadIdx.x; i < nblocks; i += 256) {
        float2 p = partial[i];
        r += (double)p.x;
        g += (double)p.y;
    }
    #pragma unroll
    for (int off = 32; off > 0; off >>= 1) {
        r += __shfl_down(r, off, 64);
        g += __shfl_down(g, off, 64);
    }
    __shared__ double s_r[4], s_g[4];
    int wid = threadIdx.x >> 6;
    if ((threadIdx.x & 63) == 0) { s_r[wid] = r; s_g[wid] = g; }
    __syncthreads();
    if (threadIdx.x == 0) {
        double rr = s_r[0] + s_r[1] + s_r[2] + s_r[3];
        double gg = s_g[0] + s_g[1] + s_g[2] + s_g[3];
        out[0] = (float)(rr * cRot + gg * cGrad);
    }
}

extern "C" void kernel_launch(void* const* d_in, const int* in_sizes, int n_in,
                              void* d_out, int out_size, void* d_ws, size_t ws_size,
                              hipStream_t stream)
{
    const float* qp   = (const float*)d_in[0];
    const float* qt   = (const float*)d_in[1];
    const float* syms = (const float*)d_in[2];

    int S  = in_sizes[2] / 4;        // 24
    int NP = in_sizes[0] / 4;        // B*H*W = 1,048,576 pixels
    int nblocks = (NP / 4) / 256;    // 1024

    // d_ws layout: partial[0..nblocks-1] (float2), then counter (uint)
    float2* partial = (float2*)d_ws;
    unsigned int* cnt = (unsigned int*)((char*)d_ws + nblocks * sizeof(float2));

    // loss = (2*sum_acos)/NP + 0.05*sum_grad/(4*NP)
    double cRot  = 2.0 / (double)NP;
    double cGrad = 0.05 / ((double)NP * 4.0);

    hipMemsetAsync(cnt, 0, sizeof(unsigned int), stream);

    if (S == 24) {
        sym_loss_main<24><<<nblocks, 256, 0, stream>>>(
            qp, qt, syms, partial, cnt, (float*)d_out, cRot, cGrad);
    } else {
        sym_loss_generic<<<nblocks, 256, 0, stream>>>(qp, qt, syms, S, partial);
        sym_loss_reduce<<<1, 256, 0, stream>>>(partial, nblocks, (float*)d_out,
                                               cRot, cGrad);
    }
}

// Round 7
// 83.620 us; speedup vs baseline: 1.2619x; 1.2619x over previous
//
#include <hip/hip_runtime.h>
#include <math.h>

// Problem constants (setup_inputs: B=16, C=4, H=256, W=256, S=24)
constexpr int Hc = 256;
constexpr int Wc = 256;
constexpr float EPSf = 1e-6f;

__device__ __forceinline__ float comp(const float4& v, int p) {
    return p == 0 ? v.x : p == 1 ? v.y : p == 2 ? v.z : v.w;
}

// Branch-free acos for x in [0,1): Abramowitz-Stegun 4.4.45, |err|<=6.7e-5
// (tolerance 1.8e-2). Raw v_sqrt_f32, no libm fixup/branches.
__device__ __forceinline__ float fast_acos01(float x) {
    float t = __builtin_amdgcn_sqrtf(1.0f - x);
    float p = fmaf(fmaf(fmaf(-0.0187293f, x, 0.0742610f), x, -0.2121144f),
                   x, 1.5707288f);
    return t * p;
}

__device__ __forceinline__ float fast_sqrt(float x) {
    return __builtin_amdgcn_sqrtf(x);   // single v_sqrt_f32 (~2 ulp)
}

// R3 structure (measured best: 84.7 us) + fast math as the ONLY delta.
// One thread = 4 consecutive pixels along w (one float4 quad); one wave =
// one image row. ALL global loads issued first (single vmcnt pipeline).
// Syms read as wave-uniform scalar loads, sym loop fully unrolled.
// Epilogue: per-block float2 partial + separate reduce kernel — DO NOT
// replace: 1024 same-address atomics (R4, +6us) and per-block
// __threadfence last-block reduction (R6, +21us) both measured worse.
template<int S>
__global__ __launch_bounds__(256, 4) void sym_loss_main(
    const float* __restrict__ qp,
    const float* __restrict__ qt,
    const float* __restrict__ syms,
    float2* __restrict__ partial)
{
    int t    = blockIdx.x * 256 + threadIdx.x;
    int lane = t & 63;           // quad index within the row
    int row  = t >> 6;           // 0 .. B*H-1
    int b    = row >> 8;         // H = 256 rows per image
    int h    = row & (Hc - 1);
    int w0   = lane << 2;

    int idx0 = (b << 18) + (h << 8) + w0;   // channel-0 flat index
    // edge pad: squared differences make the direction sign irrelevant
    int dy = (h == Hc - 1) ? -Wc : Wc;      // wave-uniform
    // x-neighbor of element 3: w0+4; lane 63 (w=255 edge) -> w=254 = idx+2
    int xo = (lane == 63) ? 2 : 4;          // in-bounds for all lanes

    // ---- phase 1: issue every global load ----
    float4 Cp[4], Yp[4], Ct[4], Yt[4];
    float  xp[4], xt[4];
    #pragma unroll
    for (int c = 0; c < 4; ++c) {
        int idx = idx0 + (c << 16);
        Cp[c] = *(const float4*)(qp + idx);
        Yp[c] = *(const float4*)(qp + idx + dy);
        xp[c] = qp[idx + xo];
        Ct[c] = *(const float4*)(qt + idx);
        Yt[c] = *(const float4*)(qt + idx + dy);
        xt[c] = qt[idx + xo];
    }

    // ---- phase 2: gradient-magnitude term ----
    float gsum = 0.0f;
    #pragma unroll
    for (int c = 0; c < 4; ++c) {
        float4 C = Cp[c], Y = Yp[c], D = Ct[c], Z = Yt[c];
        float gx, gy, a, e;
        gx = C.y - C.x; gy = Y.x - C.x;
        a = fast_sqrt(fmaf(gx, gx, fmaf(gy, gy, EPSf)));
        gx = D.y - D.x; gy = Z.x - D.x;
        e = fast_sqrt(fmaf(gx, gx, fmaf(gy, gy, EPSf)));
        gsum += fabsf(a - e);

        gx = C.z - C.y; gy = Y.y - C.y;
        a = fast_sqrt(fmaf(gx, gx, fmaf(gy, gy, EPSf)));
        gx = D.z - D.y; gy = Z.y - D.y;
        e = fast_sqrt(fmaf(gx, gx, fmaf(gy, gy, EPSf)));
        gsum += fabsf(a - e);

        gx = C.w - C.z; gy = Y.z - C.z;
        a = fast_sqrt(fmaf(gx, gx, fmaf(gy, gy, EPSf)));
        gx = D.w - D.z; gy = Z.z - D.z;
        e = fast_sqrt(fmaf(gx, gx, fmaf(gy, gy, EPSf)));
        gsum += fabsf(a - e);

        gx = xp[c] - C.w; gy = Y.w - C.w;
        a = fast_sqrt(fmaf(gx, gx, fmaf(gy, gy, EPSf)));
        gx = xt[c] - D.w; gy = Z.w - D.w;
        e = fast_sqrt(fmaf(gx, gx, fmaf(gy, gy, EPSf)));
        gsum += fabsf(a - e);
    }

    // ---- phase 3: per-pixel relative quaternion (vector part negated) ----
    float rw[4], nx[4], ny[4], nz[4];
    #pragma unroll
    for (int p = 0; p < 4; ++p) {
        float a0 = comp(Cp[0], p), a1 = comp(Cp[1], p),
              a2 = comp(Cp[2], p), a3 = comp(Cp[3], p);
        float b0 = comp(Ct[0], p), b1 = comp(Ct[1], p),
              b2 = comp(Ct[2], p), b3 = comp(Ct[3], p);

        float ss1 = fmaf(a0, a0, fmaf(a1, a1, fmaf(a2, a2, a3 * a3)));
        float ss2 = fmaf(b0, b0, fmaf(b1, b1, fmaf(b2, b2, b3 * b3)));
        float i1 = __builtin_amdgcn_rsqf(ss1);   // ss >> eps^2 here
        float i2 = __builtin_amdgcn_rsqf(ss2);
        float w1 = a0 * i1, x1 = a1 * i1, y1 = a2 * i1, z1 = a3 * i1;
        float w2 = b0 * i2, x2 = b1 * i2, y2 = b2 * i2, z2 = b3 * i2;

        rw[p] =  w2 * w1 + x2 * x1 + y2 * y1 + z2 * z1;
        float rx = -w2 * x1 + x2 * w1 - y2 * z1 + z2 * y1;
        float ry = -w2 * y1 + x2 * z1 + y2 * w1 - z2 * x1;
        float rz = -w2 * z1 - x2 * y1 + y2 * x1 + z2 * w1;
        nx[p] = -rx; ny[p] = -ry; nz[p] = -rz;   // signs [1,-1,-1,-1]
    }

    // ---- phase 4: sym search; wave-uniform scalar loads, fully unrolled ----
    const float4* __restrict__ sv4 = (const float4*)syms;
    float maxw[4] = {0.f, 0.f, 0.f, 0.f};
    #pragma unroll
    for (int s = 0; s < S; ++s) {
        float4 sv = sv4[s];
        #pragma unroll
        for (int p = 0; p < 4; ++p) {
            float d = fmaf(nz[p], sv.w,
                      fmaf(ny[p], sv.z,
                      fmaf(nx[p], sv.y, rw[p] * sv.x)));
            maxw[p] = fmaxf(maxw[p], fabsf(d));
        }
    }
    float rot = 0.0f;
    #pragma unroll
    for (int p = 0; p < 4; ++p)
        rot += fast_acos01(fminf(maxw[p], 1.0f - EPSf));
    // (x2 of 2*acos folded into reduce kernel's cRot)

    // ---- phase 5: block reduce -> one float2 partial per block ----
    #pragma unroll
    for (int off = 32; off > 0; off >>= 1) {
        rot  += __shfl_down(rot,  off, 64);
        gsum += __shfl_down(gsum, off, 64);
    }
    __shared__ float s_r[4], s_g[4];
    int wid = threadIdx.x >> 6;
    if ((threadIdx.x & 63) == 0) { s_r[wid] = rot; s_g[wid] = gsum; }
    __syncthreads();
    if (threadIdx.x == 0) {
        float2 o;
        o.x = s_r[0] + s_r[1] + s_r[2] + s_r[3];
        o.y = s_g[0] + s_g[1] + s_g[2] + s_g[3];
        partial[blockIdx.x] = o;
    }
}

// Generic-S fallback (runtime sym loop), same math
__global__ __launch_bounds__(256) void sym_loss_generic(
    const float* __restrict__ qp,
    const float* __restrict__ qt,
    const float* __restrict__ syms,
    int S,
    float2* __restrict__ partial)
{
    int t    = blockIdx.x * 256 + threadIdx.x;
    int lane = t & 63;
    int row  = t >> 6;
    int b    = row >> 8;
    int h    = row & (Hc - 1);
    int w0   = lane << 2;
    int idx0 = (b << 18) + (h << 8) + w0;
    int dy = (h == Hc - 1) ? -Wc : Wc;
    int xo = (lane == 63) ? 2 : 4;

    float4 Cp[4], Yp[4], Ct[4], Yt[4];
    float  xp[4], xt[4];
    #pragma unroll
    for (int c = 0; c < 4; ++c) {
        int idx = idx0 + (c << 16);
        Cp[c] = *(const float4*)(qp + idx);
        Yp[c] = *(const float4*)(qp + idx + dy);
        xp[c] = qp[idx + xo];
        Ct[c] = *(const float4*)(qt + idx);
        Yt[c] = *(const float4*)(qt + idx + dy);
        xt[c] = qt[idx + xo];
    }
    float gsum = 0.0f;
    #pragma unroll
    for (int c = 0; c < 4; ++c) {
        float4 C = Cp[c], Y = Yp[c], D = Ct[c], Z = Yt[c];
        float gx, gy, a, e;
        gx = C.y - C.x; gy = Y.x - C.x;
        a = fast_sqrt(fmaf(gx, gx, fmaf(gy, gy, EPSf)));
        gx = D.y - D.x; gy = Z.x - D.x;
        e = fast_sqrt(fmaf(gx, gx, fmaf(gy, gy, EPSf)));
        gsum += fabsf(a - e);
        gx = C.z - C.y; gy = Y.y - C.y;
        a = fast_sqrt(fmaf(gx, gx, fmaf(gy, gy, EPSf)));
        gx = D.z - D.y; gy = Z.y - D.y;
        e = fast_sqrt(fmaf(gx, gx, fmaf(gy, gy, EPSf)));
        gsum += fabsf(a - e);
        gx = C.w - C.z; gy = Y.z - C.z;
        a = fast_sqrt(fmaf(gx, gx, fmaf(gy, gy, EPSf)));
        gx = D.w - D.z; gy = Z.z - D.z;
        e = fast_sqrt(fmaf(gx, gx, fmaf(gy, gy, EPSf)));
        gsum += fabsf(a - e);
        gx = xp[c] - C.w; gy = Y.w - C.w;
        a = fast_sqrt(fmaf(gx, gx, fmaf(gy, gy, EPSf)));
        gx = xt[c] - D.w; gy = Z.w - D.w;
        e = fast_sqrt(fmaf(gx, gx, fmaf(gy, gy, EPSf)));
        gsum += fabsf(a - e);
    }
    float rw[4], nx[4], ny[4], nz[4];
    #pragma unroll
    for (int p = 0; p < 4; ++p) {
        float a0 = comp(Cp[0], p), a1 = comp(Cp[1], p),
              a2 = comp(Cp[2], p), a3 = comp(Cp[3], p);
        float b0 = comp(Ct[0], p), b1 = comp(Ct[1], p),
              b2 = comp(Ct[2], p), b3 = comp(Ct[3], p);
        float ss1 = fmaf(a0, a0, fmaf(a1, a1, fmaf(a2, a2, a3 * a3)));
        float ss2 = fmaf(b0, b0, fmaf(b1, b1, fmaf(b2, b2, b3 * b3)));
        float i1 = __builtin_amdgcn_rsqf(ss1);
        float i2 = __builtin_amdgcn_rsqf(ss2);
        float w1 = a0 * i1, x1 = a1 * i1, y1 = a2 * i1, z1 = a3 * i1;
        float w2 = b0 * i2, x2 = b1 * i2, y2 = b2 * i2, z2 = b3 * i2;
        rw[p] =  w2 * w1 + x2 * x1 + y2 * y1 + z2 * z1;
        float rx = -w2 * x1 + x2 * w1 - y2 * z1 + z2 * y1;
        float ry = -w2 * y1 + x2 * z1 + y2 * w1 - z2 * x1;
        float rz = -w2 * z1 - x2 * y1 + y2 * x1 + z2 * w1;
        nx[p] = -rx; ny[p] = -ry; nz[p] = -rz;
    }
    const float4* __restrict__ sv4 = (const float4*)syms;
    float maxw[4] = {0.f, 0.f, 0.f, 0.f};
    for (int s = 0; s < S; ++s) {
        float4 sv = sv4[s];
        #pragma unroll
        for (int p = 0; p < 4; ++p) {
            float d = fmaf(nz[p], sv.w,
                      fmaf(ny[p], sv.z,
                      fmaf(nx[p], sv.y, rw[p] * sv.x)));
            maxw[p] = fmaxf(maxw[p], fabsf(d));
        }
    }
    float rot = 0.0f;
    #pragma unroll
    for (int p = 0; p < 4; ++p)
        rot += fast_acos01(fminf(maxw[p], 1.0f - EPSf));
    #pragma unroll
    for (int off = 32; off > 0; off >>= 1) {
        rot  += __shfl_down(rot,  off, 64);
        gsum += __shfl_down(gsum, off, 64);
    }
    __shared__ float s_r[4], s_g[4];
    int wid = threadIdx.x >> 6;
    if ((threadIdx.x & 63) == 0) { s_r[wid] = rot; s_g[wid] = gsum; }
    __syncthreads();
    if (threadIdx.x == 0) {
        float2 o;
        o.x = s_r[0] + s_r[1] + s_r[2] + s_r[3];
        o.y = s_g[0] + s_g[1] + s_g[2] + s_g[3];
        partial[blockIdx.x] = o;
    }
}

__global__ __launch_bounds__(256) void sym_loss_reduce(
    const float2* __restrict__ partial, int nblocks,
    float* __restrict__ out, double cRot, double cGrad)
{
    double r = 0.0, g = 0.0;
    for (int i = threadIdx.x; i < nblocks; i += 256) {
        float2 p = partial[i];
        r += (double)p.x;
        g += (double)p.y;
    }
    #pragma unroll
    for (int off = 32; off > 0; off >>= 1) {
        r += __shfl_down(r, off, 64);
        g += __shfl_down(g, off, 64);
    }
    __shared__ double s_r[4], s_g[4];
    int wid = threadIdx.x >> 6;
    if ((threadIdx.x & 63) == 0) { s_r[wid] = r; s_g[wid] = g; }
    __syncthreads();
    if (threadIdx.x == 0) {
        double rr = s_r[0] + s_r[1] + s_r[2] + s_r[3];
        double gg = s_g[0] + s_g[1] + s_g[2] + s_g[3];
        out[0] = (float)(rr * cRot + gg * cGrad);
    }
}

extern "C" void kernel_launch(void* const* d_in, const int* in_sizes, int n_in,
                              void* d_out, int out_size, void* d_ws, size_t ws_size,
                              hipStream_t stream)
{
    const float* qp   = (const float*)d_in[0];
    const float* qt   = (const float*)d_in[1];
    const float* syms = (const float*)d_in[2];

    int S  = in_sizes[2] / 4;        // 24
    int NP = in_sizes[0] / 4;        // B*H*W = 1,048,576 pixels
    int nblocks = (NP / 4) / 256;    // 1024

    float2* partial = (float2*)d_ws; // every slot written each call

    // loss = (2*sum_acos)/NP + 0.05*sum_grad/(4*NP)
    double cRot  = 2.0 / (double)NP;
    double cGrad = 0.05 / ((double)NP * 4.0);

    if (S == 24) {
        sym_loss_main<24><<<nblocks, 256, 0, stream>>>(qp, qt, syms, partial);
    } else {
        sym_loss_generic<<<nblocks, 256, 0, stream>>>(qp, qt, syms, S, partial);
    }

    sym_loss_reduce<<<1, 256, 0, stream>>>(partial, nblocks, (float*)d_out,
                                           cRot, cGrad);
}

// Round 8
// 82.463 us; speedup vs baseline: 1.2796x; 1.0140x over previous
//
#include <hip/hip_runtime.h>
#include <math.h>

// Problem constants (setup_inputs: B=16, C=4, H=256, W=256, S=24)
constexpr int Hc = 256;
constexpr int Wc = 256;
constexpr float EPSf = 1e-6f;

// Branch-free acos for x in [0,1): Abramowitz-Stegun 4.4.45, |err|<=6.7e-5
// (tolerance 1.8e-2). Raw v_sqrt_f32, no libm fixup/branches.
__device__ __forceinline__ float fast_acos01(float x) {
    float t = __builtin_amdgcn_sqrtf(1.0f - x);
    float p = fmaf(fmaf(fmaf(-0.0187293f, x, 0.0742610f), x, -0.2121144f),
                   x, 1.5707288f);
    return t * p;
}

__device__ __forceinline__ float fast_sqrt(float x) {
    return __builtin_amdgcn_sqrtf(x);   // single v_sqrt_f32 (~2 ulp)
}

// 2 pixels/thread, 2048 blocks -> up to 8 blocks/CU (R7 diagnosis: kernel is
// latency-bound at 16 waves/CU because grid=1024 capped occupancy; fast-math
// cut of ~300 VALU instrs moved only ~1us). launch_bounds(256,6) caps VGPR
// at ~84 so >=6 blocks/CU are resident. Loads-first, fast math, wave-uniform
// sym scalar loads, partials + reduce kernel epilogue (R4/R6: atomics and
// last-block-fence epilogues both measured worse — do not revisit).
template<int S>
__global__ __launch_bounds__(256, 6) void sym_loss_main(
    const float* __restrict__ qp,
    const float* __restrict__ qt,
    const float* __restrict__ syms,
    float2* __restrict__ partial)
{
    int t    = blockIdx.x * 256 + threadIdx.x;   // 0 .. NP/2-1
    int pix0 = t << 1;                           // even pixel index
    int b    = pix0 >> 16;                       // / (H*W)
    int rem  = pix0 & 0xFFFF;
    int h    = rem >> 8;
    int w0   = rem & (Wc - 1);                   // even, 0..254

    int idx0 = (b << 18) + rem;                  // channel-0 flat index
    // edge pad: squared differences make the direction sign irrelevant
    int dy = (h == Hc - 1) ? -Wc : Wc;           // wave-uniform
    // x-neighbor of element 1 (w0+1): value at w0+2; thread at w0=254 owns
    // the row edge (w=255) whose duplicated diff uses w=254 = offset 0.
    int xo = (w0 == Wc - 2) ? 0 : 2;

    // ---- phase 1: issue every global load ----
    float2 Cp[4], Yp[4], Ct[4], Yt[4];
    float  xp[4], xt[4];
    #pragma unroll
    for (int c = 0; c < 4; ++c) {
        int idx = idx0 + (c << 16);
        Cp[c] = *(const float2*)(qp + idx);
        Yp[c] = *(const float2*)(qp + idx + dy);
        xp[c] = qp[idx + xo];
        Ct[c] = *(const float2*)(qt + idx);
        Yt[c] = *(const float2*)(qt + idx + dy);
        xt[c] = qt[idx + xo];
    }

    // ---- phase 2: gradient-magnitude term (2 pixels x 4 channels) ----
    float gsum = 0.0f;
    #pragma unroll
    for (int c = 0; c < 4; ++c) {
        float2 C = Cp[c], Y = Yp[c], D = Ct[c], Z = Yt[c];
        float gx, gy, a, e;
        // pixel 0: x-diff in-register
        gx = C.y - C.x; gy = Y.x - C.x;
        a = fast_sqrt(fmaf(gx, gx, fmaf(gy, gy, EPSf)));
        gx = D.y - D.x; gy = Z.x - D.x;
        e = fast_sqrt(fmaf(gx, gx, fmaf(gy, gy, EPSf)));
        gsum += fabsf(a - e);
        // pixel 1: x-diff via scalar load (or edge fold-back)
        gx = xp[c] - C.y; gy = Y.y - C.y;
        a = fast_sqrt(fmaf(gx, gx, fmaf(gy, gy, EPSf)));
        gx = xt[c] - D.y; gy = Z.y - D.y;
        e = fast_sqrt(fmaf(gx, gx, fmaf(gy, gy, EPSf)));
        gsum += fabsf(a - e);
    }

    // ---- phase 3: per-pixel relative quaternion (vector part negated) ----
    float rw[2], nx[2], ny[2], nz[2];
    #pragma unroll
    for (int p = 0; p < 2; ++p) {
        float a0 = p ? Cp[0].y : Cp[0].x, a1 = p ? Cp[1].y : Cp[1].x,
              a2 = p ? Cp[2].y : Cp[2].x, a3 = p ? Cp[3].y : Cp[3].x;
        float b0 = p ? Ct[0].y : Ct[0].x, b1 = p ? Ct[1].y : Ct[1].x,
              b2 = p ? Ct[2].y : Ct[2].x, b3 = p ? Ct[3].y : Ct[3].x;

        float ss1 = fmaf(a0, a0, fmaf(a1, a1, fmaf(a2, a2, a3 * a3)));
        float ss2 = fmaf(b0, b0, fmaf(b1, b1, fmaf(b2, b2, b3 * b3)));
        float i1 = __builtin_amdgcn_rsqf(ss1);   // ss >> eps^2 here
        float i2 = __builtin_amdgcn_rsqf(ss2);
        float w1 = a0 * i1, x1 = a1 * i1, y1 = a2 * i1, z1 = a3 * i1;
        float w2 = b0 * i2, x2 = b1 * i2, y2 = b2 * i2, z2 = b3 * i2;

        rw[p] =  w2 * w1 + x2 * x1 + y2 * y1 + z2 * z1;
        float rx = -w2 * x1 + x2 * w1 - y2 * z1 + z2 * y1;
        float ry = -w2 * y1 + x2 * z1 + y2 * w1 - z2 * x1;
        float rz = -w2 * z1 - x2 * y1 + y2 * x1 + z2 * w1;
        nx[p] = -rx; ny[p] = -ry; nz[p] = -rz;   // signs [1,-1,-1,-1]
    }

    // ---- phase 4: sym search; wave-uniform scalar loads, fully unrolled ----
    const float4* __restrict__ sv4 = (const float4*)syms;
    float m0 = 0.f, m1 = 0.f;
    #pragma unroll
    for (int s = 0; s < S; ++s) {
        float4 sv = sv4[s];
        float d0 = fmaf(nz[0], sv.w,
                   fmaf(ny[0], sv.z,
                   fmaf(nx[0], sv.y, rw[0] * sv.x)));
        float d1 = fmaf(nz[1], sv.w,
                   fmaf(ny[1], sv.z,
                   fmaf(nx[1], sv.y, rw[1] * sv.x)));
        m0 = fmaxf(m0, fabsf(d0));
        m1 = fmaxf(m1, fabsf(d1));
    }
    float rot = fast_acos01(fminf(m0, 1.0f - EPSf))
              + fast_acos01(fminf(m1, 1.0f - EPSf));
    // (x2 of 2*acos folded into reduce kernel's cRot)

    // ---- phase 5: block reduce -> one float2 partial per block ----
    #pragma unroll
    for (int off = 32; off > 0; off >>= 1) {
        rot  += __shfl_down(rot,  off, 64);
        gsum += __shfl_down(gsum, off, 64);
    }
    __shared__ float s_r[4], s_g[4];
    int wid = threadIdx.x >> 6;
    if ((threadIdx.x & 63) == 0) { s_r[wid] = rot; s_g[wid] = gsum; }
    __syncthreads();
    if (threadIdx.x == 0) {
        float2 o;
        o.x = s_r[0] + s_r[1] + s_r[2] + s_r[3];
        o.y = s_g[0] + s_g[1] + s_g[2] + s_g[3];
        partial[blockIdx.x] = o;
    }
}

// Generic-S fallback (runtime sym loop), R7 4px structure
__global__ __launch_bounds__(256) void sym_loss_generic(
    const float* __restrict__ qp,
    const float* __restrict__ qt,
    const float* __restrict__ syms,
    int S,
    float2* __restrict__ partial)
{
    int t    = blockIdx.x * 256 + threadIdx.x;
    int lane = t & 63;
    int row  = t >> 6;
    int b    = row >> 8;
    int h    = row & (Hc - 1);
    int w0   = lane << 2;
    int idx0 = (b << 18) + (h << 8) + w0;
    int dy = (h == Hc - 1) ? -Wc : Wc;
    int xo = (lane == 63) ? 2 : 4;

    float4 Cp[4], Yp[4], Ct[4], Yt[4];
    float  xp[4], xt[4];
    #pragma unroll
    for (int c = 0; c < 4; ++c) {
        int idx = idx0 + (c << 16);
        Cp[c] = *(const float4*)(qp + idx);
        Yp[c] = *(const float4*)(qp + idx + dy);
        xp[c] = qp[idx + xo];
        Ct[c] = *(const float4*)(qt + idx);
        Yt[c] = *(const float4*)(qt + idx + dy);
        xt[c] = qt[idx + xo];
    }
    float gsum = 0.0f;
    #pragma unroll
    for (int c = 0; c < 4; ++c) {
        float4 C = Cp[c], Y = Yp[c], D = Ct[c], Z = Yt[c];
        float gx, gy, a, e;
        gx = C.y - C.x; gy = Y.x - C.x;
        a = fast_sqrt(fmaf(gx, gx, fmaf(gy, gy, EPSf)));
        gx = D.y - D.x; gy = Z.x - D.x;
        e = fast_sqrt(fmaf(gx, gx, fmaf(gy, gy, EPSf)));
        gsum += fabsf(a - e);
        gx = C.z - C.y; gy = Y.y - C.y;
        a = fast_sqrt(fmaf(gx, gx, fmaf(gy, gy, EPSf)));
        gx = D.z - D.y; gy = Z.y - D.y;
        e = fast_sqrt(fmaf(gx, gx, fmaf(gy, gy, EPSf)));
        gsum += fabsf(a - e);
        gx = C.w - C.z; gy = Y.z - C.z;
        a = fast_sqrt(fmaf(gx, gx, fmaf(gy, gy, EPSf)));
        gx = D.w - D.z; gy = Z.z - D.z;
        e = fast_sqrt(fmaf(gx, gx, fmaf(gy, gy, EPSf)));
        gsum += fabsf(a - e);
        gx = xp[c] - C.w; gy = Y.w - C.w;
        a = fast_sqrt(fmaf(gx, gx, fmaf(gy, gy, EPSf)));
        gx = xt[c] - D.w; gy = Z.w - D.w;
        e = fast_sqrt(fmaf(gx, gx, fmaf(gy, gy, EPSf)));
        gsum += fabsf(a - e);
    }
    float rw[4], nx[4], ny[4], nz[4];
    #pragma unroll
    for (int p = 0; p < 4; ++p) {
        float a0 = ((const float*)&Cp[0])[p], a1 = ((const float*)&Cp[1])[p],
              a2 = ((const float*)&Cp[2])[p], a3 = ((const float*)&Cp[3])[p];
        float b0 = ((const float*)&Ct[0])[p], b1 = ((const float*)&Ct[1])[p],
              b2 = ((const float*)&Ct[2])[p], b3 = ((const float*)&Ct[3])[p];
        float ss1 = fmaf(a0, a0, fmaf(a1, a1, fmaf(a2, a2, a3 * a3)));
        float ss2 = fmaf(b0, b0, fmaf(b1, b1, fmaf(b2, b2, b3 * b3)));
        float i1 = __builtin_amdgcn_rsqf(ss1);
        float i2 = __builtin_amdgcn_rsqf(ss2);
        float w1 = a0 * i1, x1 = a1 * i1, y1 = a2 * i1, z1 = a3 * i1;
        float w2 = b0 * i2, x2 = b1 * i2, y2 = b2 * i2, z2 = b3 * i2;
        rw[p] =  w2 * w1 + x2 * x1 + y2 * y1 + z2 * z1;
        float rx = -w2 * x1 + x2 * w1 - y2 * z1 + z2 * y1;
        float ry = -w2 * y1 + x2 * z1 + y2 * w1 - z2 * x1;
        float rz = -w2 * z1 - x2 * y1 + y2 * x1 + z2 * w1;
        nx[p] = -rx; ny[p] = -ry; nz[p] = -rz;
    }
    const float4* __restrict__ sv4 = (const float4*)syms;
    float maxw[4] = {0.f, 0.f, 0.f, 0.f};
    for (int s = 0; s < S; ++s) {
        float4 sv = sv4[s];
        #pragma unroll
        for (int p = 0; p < 4; ++p) {
            float d = fmaf(nz[p], sv.w,
                      fmaf(ny[p], sv.z,
                      fmaf(nx[p], sv.y, rw[p] * sv.x)));
            maxw[p] = fmaxf(maxw[p], fabsf(d));
        }
    }
    float rot = 0.0f;
    #pragma unroll
    for (int p = 0; p < 4; ++p)
        rot += fast_acos01(fminf(maxw[p], 1.0f - EPSf));
    #pragma unroll
    for (int off = 32; off > 0; off >>= 1) {
        rot  += __shfl_down(rot,  off, 64);
        gsum += __shfl_down(gsum, off, 64);
    }
    __shared__ float s_r[4], s_g[4];
    int wid = threadIdx.x >> 6;
    if ((threadIdx.x & 63) == 0) { s_r[wid] = rot; s_g[wid] = gsum; }
    __syncthreads();
    if (threadIdx.x == 0) {
        float2 o;
        o.x = s_r[0] + s_r[1] + s_r[2] + s_r[3];
        o.y = s_g[0] + s_g[1] + s_g[2] + s_g[3];
        partial[blockIdx.x] = o;
    }
}

__global__ __launch_bounds__(256) void sym_loss_reduce(
    const float2* __restrict__ partial, int nblocks,
    float* __restrict__ out, double cRot, double cGrad)
{
    double r = 0.0, g = 0.0;
    for (int i = threadIdx.x; i < nblocks; i += 256) {
        float2 p = partial[i];
        r += (double)p.x;
        g += (double)p.y;
    }
    #pragma unroll
    for (int off = 32; off > 0; off >>= 1) {
        r += __shfl_down(r, off, 64);
        g += __shfl_down(g, off, 64);
    }
    __shared__ double s_r[4], s_g[4];
    int wid = threadIdx.x >> 6;
    if ((threadIdx.x & 63) == 0) { s_r[wid] = r; s_g[wid] = g; }
    __syncthreads();
    if (threadIdx.x == 0) {
        double rr = s_r[0] + s_r[1] + s_r[2] + s_r[3];
        double gg = s_g[0] + s_g[1] + s_g[2] + s_g[3];
        out[0] = (float)(rr * cRot + gg * cGrad);
    }
}

extern "C" void kernel_launch(void* const* d_in, const int* in_sizes, int n_in,
                              void* d_out, int out_size, void* d_ws, size_t ws_size,
                              hipStream_t stream)
{
    const float* qp   = (const float*)d_in[0];
    const float* qt   = (const float*)d_in[1];
    const float* syms = (const float*)d_in[2];

    int S  = in_sizes[2] / 4;        // 24
    int NP = in_sizes[0] / 4;        // B*H*W = 1,048,576 pixels

    float2* partial = (float2*)d_ws; // every slot written each call

    // loss = (2*sum_acos)/NP + 0.05*sum_grad/(4*NP)
    double cRot  = 2.0 / (double)NP;
    double cGrad = 0.05 / ((double)NP * 4.0);

    int nblocks;
    if (S == 24) {
        nblocks = NP / 512;          // 2 px/thread * 256 threads = 2048 blocks
        sym_loss_main<24><<<nblocks, 256, 0, stream>>>(qp, qt, syms, partial);
    } else {
        nblocks = (NP / 4) / 256;
        sym_loss_generic<<<nblocks, 256, 0, stream>>>(qp, qt, syms, S, partial);
    }

    sym_loss_reduce<<<1, 256, 0, stream>>>(partial, nblocks, (float*)d_out,
                                           cRot, cGrad);
}